// Round 2
// baseline (1485.634 us; speedup 1.0000x reference)
//
#include <hip/hip_runtime.h>
#include <cstdint>
#include <cstddef>

#define B_    32
#define L_    1536
#define D_    512
#define DFF_  2048
#define TOPK  7

typedef __attribute__((ext_vector_type(8))) short bf16x8;
typedef __attribute__((ext_vector_type(4))) float f32x4;
typedef __attribute__((ext_vector_type(8))) unsigned short u16x8;

__device__ __forceinline__ float b2f(unsigned short u){
  union { unsigned int i; float f; } v; v.i = ((unsigned int)u) << 16; return v.f;
}
__device__ __forceinline__ unsigned short f2b(float f){
  union { float f; unsigned int i; } v; v.f = f;
  unsigned int i = v.i;
  i += 0x7FFFu + ((i >> 16) & 1u);       // RNE
  return (unsigned short)(i >> 16);
}

// async global->LDS, 16B per lane; LDS dest = wave-uniform base + lane*16.
// Direct C-style casts -> clang addrspacecast (correct flat->LDS lowering),
// and strips const to match the builtin's (void AS1*, void AS3*) signature.
__device__ __forceinline__ void gload16(const unsigned short* g, const unsigned short* l){
  __builtin_amdgcn_global_load_lds(
      (__attribute__((address_space(1))) void*)(g),
      (__attribute__((address_space(3))) void*)(l), 16, 0, 0);
}

// ---------------------------------------------------------------------------
// bf16 GEMM, C = A(MxK, row-major) * Bt(NxK, row-major)^T + bias [+ add]
// 128x128 tile, BK=32, 4 waves (each 64x64 via 4x4 frags of 16x16x32 MFMA).
// EPI 0: bf16 out = acc+bias ; EPI 1: bf16 out = relu(acc+bias)
// EPI 2: f32  out = acc+bias+addsrc
// ---------------------------------------------------------------------------
template<int EPI>
__global__ __launch_bounds__(256, 2)
void gemm_bt(const unsigned short* __restrict__ A, int lda,
             const unsigned short* __restrict__ Bt, int ldb,
             const float* __restrict__ bias,
             const float* __restrict__ addsrc,
             void* __restrict__ Cout, int ldc,
             int K, int tilesN)
{
  __shared__ unsigned short Asm[128*32];
  __shared__ unsigned short Bsm[128*32];
  const int tid = threadIdx.x;
  const int w = tid >> 6, l = tid & 63;
  const int bid = blockIdx.x;
  const int tn = bid % tilesN, tm = bid / tilesN;
  const size_t m0 = (size_t)tm * 128, n0 = (size_t)tn * 128;

  // staging geometry: chunk c covers rows [c*16, c*16+16), lane l -> row c*16+l/4, k=(l%4)*8
  const int c0 = w, c1 = 4 + w;
  const int r0 = c0*16 + (l>>2), r1 = c1*16 + (l>>2);
  const int sk = (l & 3) * 8;
  const unsigned short* gA0 = A  + (m0 + r0) * (size_t)lda + sk;
  const unsigned short* gA1 = A  + (m0 + r1) * (size_t)lda + sk;
  const unsigned short* gB0 = Bt + (n0 + r0) * (size_t)ldb + sk;
  const unsigned short* gB1 = Bt + (n0 + r1) * (size_t)ldb + sk;
  const unsigned short* lA0 = Asm + c0*512;
  const unsigned short* lA1 = Asm + c1*512;
  const unsigned short* lB0 = Bsm + c0*512;
  const unsigned short* lB1 = Bsm + c1*512;

  const int wr = (w >> 1) * 64, wc = (w & 1) * 64;
  const int lr = l & 15, kq = (l >> 4) * 8;

  f32x4 acc[4][4];
  #pragma unroll
  for (int i=0;i<4;i++)
    #pragma unroll
    for (int j=0;j<4;j++) acc[i][j] = f32x4{0.f,0.f,0.f,0.f};

  const int nK = K >> 5;
  for (int kt = 0; kt < nK; ++kt){
    gload16(gA0, lA0); gload16(gA1, lA1);
    gload16(gB0, lB0); gload16(gB1, lB1);
    gA0 += 32; gA1 += 32; gB0 += 32; gB1 += 32;
    __syncthreads();               // drains vmcnt -> staged data visible
    bf16x8 af[4], bfr[4];
    #pragma unroll
    for (int i=0;i<4;i++) af[i]  = *(const bf16x8*)(Asm + (wr + i*16 + lr)*32 + kq);
    #pragma unroll
    for (int i=0;i<4;i++) bfr[i] = *(const bf16x8*)(Bsm + (wc + i*16 + lr)*32 + kq);
    #pragma unroll
    for (int mi=0;mi<4;mi++)
      #pragma unroll
      for (int ni=0;ni<4;ni++)
        acc[mi][ni] = __builtin_amdgcn_mfma_f32_16x16x32_bf16(af[mi], bfr[ni], acc[mi][ni], 0,0,0);
    __syncthreads();
  }

  const int fq = l >> 4;
  #pragma unroll
  for (int mi=0;mi<4;mi++){
    #pragma unroll
    for (int j=0;j<4;j++){
      const size_t r = m0 + wr + mi*16 + fq*4 + j;
      #pragma unroll
      for (int ni=0;ni<4;ni++){
        const size_t c = n0 + wc + ni*16 + lr;
        float v = acc[mi][ni][j] + bias[c];
        if (EPI == 1) v = fmaxf(v, 0.f);
        if (EPI == 2){
          ((float*)Cout)[r*(size_t)ldc + c] = v + addsrc[r*(size_t)ldc + c];
        } else {
          ((unsigned short*)Cout)[r*(size_t)ldc + c] = f2b(v);
        }
      }
    }
  }
}

// ---------------------------------------------------------------------------
// Gram autocorrelation: mean_value[b,tau] += (1/512) * sum_{(t-s)%L==tau} q_t . k_s
// One block = (b, 128-row q tile, 128-row k tile). Same MFMA core; epilogue bins
// by (t-s) into LDS then global-atomics 255 taus.
// ---------------------------------------------------------------------------
__global__ __launch_bounds__(256, 2)
void gram_corr(const unsigned short* __restrict__ qkv, float* __restrict__ mv)
{
  __shared__ unsigned short Asm[128*32];
  __shared__ unsigned short Bsm[128*32];
  __shared__ float bins[255];
  const int tid = threadIdx.x;
  const int w = tid >> 6, l = tid & 63;
  const int b = blockIdx.z, tT = blockIdx.y, tS = blockIdx.x;
  const size_t base = (size_t)b * L_ * 1536;
  const unsigned short* Aq = qkv + base + (size_t)tT*128*1536;        // q cols [0,512)
  const unsigned short* Bk = qkv + base + (size_t)tS*128*1536 + 512;  // k cols [512,1024)
  if (tid < 255) bins[tid] = 0.f;

  const int c0 = w, c1 = 4 + w;
  const int r0 = c0*16 + (l>>2), r1 = c1*16 + (l>>2);
  const int sk = (l & 3) * 8;
  const unsigned short* gA0 = Aq + (size_t)r0*1536 + sk;
  const unsigned short* gA1 = Aq + (size_t)r1*1536 + sk;
  const unsigned short* gB0 = Bk + (size_t)r0*1536 + sk;
  const unsigned short* gB1 = Bk + (size_t)r1*1536 + sk;
  const unsigned short* lA0 = Asm + c0*512;
  const unsigned short* lA1 = Asm + c1*512;
  const unsigned short* lB0 = Bsm + c0*512;
  const unsigned short* lB1 = Bsm + c1*512;

  const int wr = (w >> 1) * 64, wc = (w & 1) * 64;
  const int lr = l & 15, kq = (l >> 4) * 8;

  f32x4 acc[4][4];
  #pragma unroll
  for (int i=0;i<4;i++)
    #pragma unroll
    for (int j=0;j<4;j++) acc[i][j] = f32x4{0.f,0.f,0.f,0.f};

  for (int kt = 0; kt < 16; ++kt){
    gload16(gA0, lA0); gload16(gA1, lA1);
    gload16(gB0, lB0); gload16(gB1, lB1);
    gA0 += 32; gA1 += 32; gB0 += 32; gB1 += 32;
    __syncthreads();
    bf16x8 af[4], bfr[4];
    #pragma unroll
    for (int i=0;i<4;i++) af[i]  = *(const bf16x8*)(Asm + (wr + i*16 + lr)*32 + kq);
    #pragma unroll
    for (int i=0;i<4;i++) bfr[i] = *(const bf16x8*)(Bsm + (wc + i*16 + lr)*32 + kq);
    #pragma unroll
    for (int mi=0;mi<4;mi++)
      #pragma unroll
      for (int ni=0;ni<4;ni++)
        acc[mi][ni] = __builtin_amdgcn_mfma_f32_16x16x32_bf16(af[mi], bfr[ni], acc[mi][ni], 0,0,0);
    __syncthreads();
  }

  const int fq = l >> 4;
  #pragma unroll
  for (int mi=0;mi<4;mi++)
    #pragma unroll
    for (int j=0;j<4;j++){
      const int rp = wr + mi*16 + fq*4 + j;
      #pragma unroll
      for (int ni=0;ni<4;ni++){
        const int cp = wc + ni*16 + lr;
        atomicAdd(&bins[rp - cp + 127], acc[mi][ni][j]);
      }
    }
  __syncthreads();
  if (tid < 255){
    int dd = (tT - tS)*128 + (tid - 127);
    int tau = dd % L_; if (tau < 0) tau += L_;
    atomicAdd(&mv[(size_t)b*L_ + tau], bins[tid] * (1.f/512.f));
  }
}

// ---------------------------------------------------------------------------
// top-7 over batch-mean of mean_value (tie -> lowest index, matching lax.top_k),
// then per-batch softmax over mean_value[b, idx].
// ---------------------------------------------------------------------------
__global__ void topk_softmax(const float* __restrict__ mv, int* __restrict__ idxo,
                             float* __restrict__ wo)
{
  __shared__ float cm[L_];
  __shared__ float bvv[256];
  __shared__ int   bii[256];
  __shared__ int   sel[TOPK];
  const int tid = threadIdx.x;
  for (int t = tid; t < L_; t += 256){
    float s = 0.f;
    for (int b = 0; b < B_; ++b) s += mv[(size_t)b*L_ + t];
    cm[t] = s;
  }
  __syncthreads();
  for (int it = 0; it < TOPK; ++it){
    float best = -1e30f; int bidx = L_;
    for (int t = tid; t < L_; t += 256){
      float v = cm[t];
      if (v > best){ best = v; bidx = t; }
    }
    bvv[tid] = best; bii[tid] = bidx;
    __syncthreads();
    if (tid == 0){
      float g = -1e30f; int gi = L_;
      for (int i = 0; i < 256; ++i){
        if (bvv[i] > g || (bvv[i] == g && bii[i] < gi)){ g = bvv[i]; gi = bii[i]; }
      }
      sel[it] = gi; cm[gi] = -1e30f; idxo[it] = gi;
    }
    __syncthreads();
  }
  if (tid < B_){
    float wv[TOPK]; float m = -1e30f;
    #pragma unroll
    for (int i=0;i<TOPK;i++){ wv[i] = mv[(size_t)tid*L_ + sel[i]]; m = fmaxf(m, wv[i]); }
    float s = 0.f;
    #pragma unroll
    for (int i=0;i<TOPK;i++){ wv[i] = expf(wv[i]-m); s += wv[i]; }
    #pragma unroll
    for (int i=0;i<TOPK;i++) wo[tid*TOPK + i] = wv[i]/s;
  }
}

// agg[b,t,:] = sum_i w[b,i] * v[b,(t+idx[i])%L,:]
__global__ __launch_bounds__(256)
void agg_kernel(const unsigned short* __restrict__ qkv, const int* __restrict__ idx,
                const float* __restrict__ wsm, unsigned short* __restrict__ aggo)
{
  const int b = blockIdx.y;
  const int t0 = blockIdx.x * 64;
  const int tid = threadIdx.x, w = tid >> 6, l = tid & 63;
  int sh[TOPK]; float ww[TOPK];
  #pragma unroll
  for (int i=0;i<TOPK;i++){ sh[i] = idx[i]; ww[i] = wsm[b*TOPK + i]; }
  const size_t vbase = (size_t)b*L_*1536 + 1024;   // v cols [1024,1536)
  for (int r = w; r < 64; r += 4){
    const int t = t0 + r;
    float a[8] = {0,0,0,0,0,0,0,0};
    #pragma unroll
    for (int i=0;i<TOPK;i++){
      int s = t + sh[i]; if (s >= L_) s -= L_;
      const u16x8 vv = *(const u16x8*)(qkv + vbase + (size_t)s*1536 + l*8);
      const float wi = ww[i];
      #pragma unroll
      for (int e=0;e<8;e++) a[e] += wi * b2f(vv[e]);
    }
    u16x8 o;
    #pragma unroll
    for (int e=0;e<8;e++) o[e] = f2b(a[e]);
    *(u16x8*)(aggo + ((size_t)b*L_ + t)*D_ + l*8) = o;
  }
}

// out = in - movavg_25(in) along L (edge-replicated window), optional bf16 copy
template<bool WB>
__global__ __launch_bounds__(512)
void movavg_kernel(const float* __restrict__ in, float* __restrict__ outf,
                   unsigned short* __restrict__ outb)
{
  const int b = blockIdx.y;
  const int t0 = blockIdx.x * 128;
  const int d = threadIdx.x;
  const float* p = in + (size_t)b*L_*D_ + d;
  float s = 0.f;
  #pragma unroll
  for (int j=-12;j<=12;j++){
    int jj = t0 + j; jj = jj < 0 ? 0 : (jj >= L_ ? L_-1 : jj);
    s += p[(size_t)jj*D_];
  }
  for (int t = t0; t < t0+128; ++t){
    float val = p[(size_t)t*D_];
    float o = val - s * (1.f/25.f);
    size_t off = ((size_t)b*L_ + t)*D_ + d;
    outf[off] = o;
    if (WB) outb[off] = f2b(o);
    int ja = t+13; if (ja >= L_) ja = L_-1;
    int jr = t-12; if (jr < 0) jr = 0;
    s += p[(size_t)ja*D_] - p[(size_t)jr*D_];
  }
}

__global__ void cast_f32_bf16(const float* __restrict__ in, unsigned short* __restrict__ o, int n8){
  int i = blockIdx.x*blockDim.x + threadIdx.x;
  if (i >= n8) return;
  const float4* p = (const float4*)in;
  float4 a = p[2*i], b4 = p[2*i+1];
  u16x8 r;
  r[0]=f2b(a.x);  r[1]=f2b(a.y);  r[2]=f2b(a.z);  r[3]=f2b(a.w);
  r[4]=f2b(b4.x); r[5]=f2b(b4.y); r[6]=f2b(b4.z); r[7]=f2b(b4.w);
  ((u16x8*)o)[i] = r;
}

// Wt[n][k] = (bf16) Wsrc[k][n];  Wsrc is K x N row-major
__global__ void transpose_cast(const float* __restrict__ Wsrc, unsigned short* __restrict__ Wt,
                               int K, int N){
  __shared__ float t[32][33];
  int n0 = blockIdx.x*32, k0 = blockIdx.y*32;
  int tx = threadIdx.x & 31, ty = threadIdx.x >> 5;
  #pragma unroll
  for (int i = ty; i < 32; i += 8) t[i][tx] = Wsrc[(size_t)(k0+i)*N + (n0+tx)];
  __syncthreads();
  #pragma unroll
  for (int i = ty; i < 32; i += 8) Wt[(size_t)(n0+i)*K + (k0+tx)] = f2b(t[tx][i]);
}

__global__ void concat_bias(const float* __restrict__ bq, const float* __restrict__ bk,
                            const float* __restrict__ bv, float* __restrict__ o){
  int i = blockIdx.x*256 + threadIdx.x;
  if (i < 512) o[i] = bq[i];
  else if (i < 1024) o[i] = bk[i-512];
  else if (i < 1536) o[i] = bv[i-1024];
}

// ---------------------------------------------------------------------------
extern "C" void kernel_launch(void* const* d_in, const int* in_sizes, int n_in,
                              void* d_out, int out_size, void* d_ws, size_t ws_size,
                              hipStream_t stream)
{
  const float* x  = (const float*)d_in[0];
  const float* Wq = (const float*)d_in[1];
  const float* bq = (const float*)d_in[2];
  const float* Wk = (const float*)d_in[3];
  const float* bk = (const float*)d_in[4];
  const float* Wv = (const float*)d_in[5];
  const float* bv = (const float*)d_in[6];
  const float* Wo = (const float*)d_in[7];
  const float* bo = (const float*)d_in[8];
  const float* W1 = (const float*)d_in[9];
  const float* b1 = (const float*)d_in[10];
  const float* W2 = (const float*)d_in[11];
  const float* b2 = (const float*)d_in[12];
  float* out = (float*)d_out;

  const size_t M = (size_t)B_ * L_;            // 49152
  // workspace arena (lifetimes overlapped; u lives in d_out until final stage):
  constexpr size_t SZ_QKV = (size_t)49152*1536*2;  // 151.0 MB
  constexpr size_t SZ_XB  = (size_t)49152*512*2;   //  50.3 MB (xb -> agg; h spans qkv+xb)
  constexpr size_t SZ_F32 = (size_t)49152*512*4;   // 100.7 MB
  constexpr size_t O_QKV  = 0;
  constexpr size_t O_XB   = SZ_QKV;
  constexpr size_t O_X1   = SZ_QKV + SZ_XB;        // x1 then z
  constexpr size_t O_UB   = O_X1 + SZ_F32;
  constexpr size_t O_WQKV = O_UB + SZ_XB;
  constexpr size_t O_WO   = O_WQKV + (size_t)1536*512*2;
  constexpr size_t O_W1   = O_WO + (size_t)512*512*2;
  constexpr size_t O_W2   = O_W1 + (size_t)2048*512*2;
  constexpr size_t O_BC   = O_W2 + (size_t)512*2048*2;
  constexpr size_t O_MV   = O_BC + (size_t)1536*4;
  constexpr size_t O_IDX  = O_MV + (size_t)32*1536*4;
  constexpr size_t O_WSM  = O_IDX + 256;

  char* ws = (char*)d_ws;
  unsigned short* qkv    = (unsigned short*)(ws + O_QKV);
  unsigned short* xb     = (unsigned short*)(ws + O_XB);   // x bf16, later agg
  unsigned short* hbuf   = (unsigned short*)(ws + O_QKV);  // FFN hidden (reuses qkv+xb)
  float*          x1     = (float*)(ws + O_X1);            // x + attnOut, later z
  float*          u      = (float*)d_out;                  // decomposed x (d_out as scratch)
  unsigned short* ub     = (unsigned short*)(ws + O_UB);   // u in bf16
  unsigned short* Wqkv_t = (unsigned short*)(ws + O_WQKV);
  unsigned short* Wo_t   = (unsigned short*)(ws + O_WO);
  unsigned short* W1_t   = (unsigned short*)(ws + O_W1);
  unsigned short* W2_t   = (unsigned short*)(ws + O_W2);
  float*          bcat   = (float*)(ws + O_BC);
  float*          mv     = (float*)(ws + O_MV);
  int*            idxb   = (int*)(ws + O_IDX);
  float*          wsm    = (float*)(ws + O_WSM);

  hipMemsetAsync(mv, 0, (size_t)B_*L_*sizeof(float), stream);

  // prep: casts + weight transposes
  int n8 = (int)(M * D_ / 8);
  cast_f32_bf16<<<(n8 + 255)/256, 256, 0, stream>>>(x, xb, n8);
  transpose_cast<<<dim3(D_/32, D_/32), 256, 0, stream>>>(Wq, Wqkv_t,            D_, D_);
  transpose_cast<<<dim3(D_/32, D_/32), 256, 0, stream>>>(Wk, Wqkv_t + 512*512,  D_, D_);
  transpose_cast<<<dim3(D_/32, D_/32), 256, 0, stream>>>(Wv, Wqkv_t + 1024*512, D_, D_);
  transpose_cast<<<dim3(D_/32, D_/32), 256, 0, stream>>>(Wo, Wo_t, D_, D_);
  transpose_cast<<<dim3(DFF_/32, D_/32), 256, 0, stream>>>(W1, W1_t, D_, DFF_);
  transpose_cast<<<dim3(D_/32, DFF_/32), 256, 0, stream>>>(W2, W2_t, DFF_, D_);
  concat_bias<<<6, 256, 0, stream>>>(bq, bk, bv, bcat);

  // qkv = x @ [Wq|Wk|Wv] + [bq|bk|bv]   (M x 1536, bf16)
  gemm_bt<0><<<dim3((M/128)*(1536/128)), 256, 0, stream>>>(
      xb, D_, Wqkv_t, D_, bcat, nullptr, qkv, 1536, D_, 1536/128);

  // mean autocorrelation + top-7 + per-batch softmax weights
  gram_corr<<<dim3(12, 12, B_), 256, 0, stream>>>(qkv, mv);
  topk_softmax<<<1, 256, 0, stream>>>(mv, idxb, wsm);

  // agg = sum_i w_i * shift(v, idx_i)
  agg_kernel<<<dim3(L_/64, B_), 256, 0, stream>>>(qkv, idxb, wsm, xb);

  // x1 = x + agg @ Wo + bo
  gemm_bt<2><<<dim3((M/128)*(D_/128)), 256, 0, stream>>>(
      xb, D_, Wo_t, D_, bo, x, x1, D_, D_, D_/128);

  // u = x1 - movavg(x1)  (f32 into d_out + bf16 copy)
  movavg_kernel<true><<<dim3(L_/128, B_), 512, 0, stream>>>(x1, u, ub);

  // h = relu(u @ W1 + b1)
  gemm_bt<1><<<dim3((M/128)*(DFF_/128)), 256, 0, stream>>>(
      ub, D_, W1_t, D_, b1, nullptr, hbuf, DFF_, D_, DFF_/128);

  // z = u + h @ W2 + b2   (into x1's slot; u's last read)
  gemm_bt<2><<<dim3((M/128)*(D_/128)), 256, 0, stream>>>(
      hbuf, DFF_, W2_t, DFF_, b2, u, x1, D_, DFF_, D_/128);

  // res = z - movavg(z)   (overwrites d_out)
  movavg_kernel<false><<<dim3(L_/128, B_), 512, 0, stream>>>(x1, out, nullptr);

  (void)in_sizes; (void)n_in; (void)out_size; (void)ws_size;
}